// Round 2
// baseline (515.773 us; speedup 1.0000x reference)
//
#include <hip/hip_runtime.h>

#define BS 4
#define NS 16384
#define S_SAMP 8
#define CPL 64
#define RES 128
#define IN_DIM 192
#define NPTS (BS * NS)                 // 65536
#define PL_STRIDE (RES * RES * CPL)    // 1048576 floats per (batch,plane)
#define PLANES_T_FLOATS (BS * 3 * PL_STRIDE)

// ---------------------------------------------------------------------------
// Kernel 1: transpose planes [B,C,H,W] -> [B,pl,H,W,C] so channel gathers are
// coalesced 256B wave loads (lane = channel).
// ---------------------------------------------------------------------------
__global__ __launch_bounds__(256) void transpose_planes(
    const float* __restrict__ xz, const float* __restrict__ xy,
    const float* __restrict__ yz, float* __restrict__ T) {
  __shared__ float tile[64][33];  // +1 pad: conflict-free both phases
  int blk = blockIdx.x;
  int xt = blk & 3;             // x-tile (32 wide)
  int y  = (blk >> 2) & 127;
  int pl = (blk >> 9) % 3;
  int b  = blk / 1536;
  const float* src = (pl == 0) ? xz : ((pl == 1) ? xy : yz);
  src += (size_t)b * CPL * RES * RES + (size_t)y * RES + xt * 32;
  int tid = threadIdx.x;
  int xl = tid & 31, c0 = tid >> 5;
#pragma unroll
  for (int r = 0; r < 8; ++r) {
    int c = c0 + (r << 3);
    tile[c][xl] = src[(size_t)c * RES * RES + xl];  // coalesced over xl
  }
  __syncthreads();
  float* dst = T + ((size_t)(b * 3 + pl) * RES * RES + (size_t)y * RES + xt * 32) * CPL;
  int c2 = tid & 63, x0 = tid >> 6;
#pragma unroll
  for (int r = 0; r < 8; ++r) {
    int xl2 = x0 + (r << 2);
    dst[(size_t)xl2 * CPL + c2] = tile[c2][xl2];    // coalesced over c2
  }
}

// ---------------------------------------------------------------------------
// Kernel 2: fold W_out@W_v -> WcT (transposed for coalesced reads), bc=W_out@b_v
// ---------------------------------------------------------------------------
__global__ __launch_bounds__(192) void precompute_wc(
    const float* __restrict__ W_v, const float* __restrict__ b_v,
    const float* __restrict__ W_out, float* __restrict__ WcT,
    float* __restrict__ bc) {
  int j = threadIdx.x;
  int k = blockIdx.x;
  if (k < IN_DIM) {
    float acc = 0.f;
    for (int m = 0; m < IN_DIM; ++m)
      acc += W_out[j * IN_DIM + m] * W_v[m * IN_DIM + k];
    WcT[k * IN_DIM + j] = acc;  // WcT[k][j] = Wc[j][k]
  } else {
    float acc = 0.f;
    for (int m = 0; m < IN_DIM; ++m)
      acc += W_out[j * IN_DIM + m] * b_v[m];
    bc[j] = acc;
  }
}

// ---------------------------------------------------------------------------
// Bilinear sample: plane base points at [H,W,C] block; lane = channel.
// Matches reference math exactly (clip -> *127 -> floor -> border clamp).
// ---------------------------------------------------------------------------
__device__ __forceinline__ float bilerp(const float* __restrict__ pb, float u,
                                        float v, int lane) {
  u = fminf(fmaxf(u, 0.f), 1.f) * 127.f;
  v = fminf(fmaxf(v, 0.f), 1.f) * 127.f;
  float xf = floorf(u), yf = floorf(v);
  int x0 = (int)xf, y0 = (int)yf;
  int x1 = min(x0 + 1, 127), y1 = min(y0 + 1, 127);
  float wx = u - xf, wy = v - yf;
  float f00 = pb[(y0 * RES + x0) * CPL + lane];
  float f01 = pb[(y0 * RES + x1) * CPL + lane];
  float f10 = pb[(y1 * RES + x0) * CPL + lane];
  float f11 = pb[(y1 * RES + x1) * CPL + lane];
  return f00 * (1.f - wx) * (1.f - wy) + f01 * wx * (1.f - wy) +
         f10 * (1.f - wx) * wy + f11 * wx * wy;
}

// ---------------------------------------------------------------------------
// Kernel 3: one wave per query point.
//   feature (12 taps) -> LDS -> off/wt matvec (lanes 0..31, float4 + 4 accs) ->
//   8 aux samples (96 taps) -> waux = sum_s wt_s * aux_s, swt = sum wt.
// feature goes straight into d_out (residual term), waux/swt to ws.
// ---------------------------------------------------------------------------
__global__ __launch_bounds__(256) void fused_sample(
    const float* __restrict__ qpos, const float* __restrict__ planesT,
    const float* __restrict__ W_off, const float* __restrict__ b_off,
    const float* __restrict__ W_wt, const float* __restrict__ b_wt,
    float* __restrict__ waux, float* __restrict__ swtg,
    float* __restrict__ featg) {
  __shared__ float feat_lds[4][IN_DIM];
  __shared__ float offwt[4][32];  // 0..23 = off, 24..31 = wt
  int w = threadIdx.x >> 6, lane = threadIdx.x & 63;
  int p = (blockIdx.x << 2) + w;
  int b = p >> 14;  // NS = 16384 points per batch
  float qx = qpos[p * 3 + 0], qy = qpos[p * 3 + 1], qz = qpos[p * 3 + 2];
  const float* Tb = planesT + (size_t)b * 3 * PL_STRIDE;

  float f0 = bilerp(Tb, qx, qz, lane);                  // xz plane: (x,z)
  float f1 = bilerp(Tb + PL_STRIDE, qx, qy, lane);      // xy plane: (x,y)
  float f2 = bilerp(Tb + 2 * PL_STRIDE, qy, qz, lane);  // yz plane: (y,z)
  feat_lds[w][lane] = f0;
  feat_lds[w][64 + lane] = f1;
  feat_lds[w][128 + lane] = f2;
  __syncthreads();

  if (lane < 32) {
    const float* row;
    float bias;
    if (lane < 24) { row = W_off + lane * IN_DIM; bias = b_off[lane]; }
    else           { row = W_wt + (lane - 24) * IN_DIM; bias = b_wt[lane - 24]; }
    const float4* r4 = (const float4*)row;
    float a0 = 0.f, a1 = 0.f, a2 = 0.f, a3 = 0.f;
#pragma unroll 4
    for (int k4 = 0; k4 < IN_DIM / 4; ++k4) {
      float4 rv = r4[k4];
      a0 += rv.x * feat_lds[w][4 * k4 + 0];
      a1 += rv.y * feat_lds[w][4 * k4 + 1];
      a2 += rv.z * feat_lds[w][4 * k4 + 2];
      a3 += rv.w * feat_lds[w][4 * k4 + 3];
    }
    offwt[w][lane] = bias + ((a0 + a1) + (a2 + a3));
  }
  __syncthreads();

  float wa0 = 0.f, wa1 = 0.f, wa2 = 0.f, swt = 0.f;
#pragma unroll 2
  for (int s = 0; s < S_SAMP; ++s) {
    float wt = offwt[w][24 + s];
    float px = qx + offwt[w][3 * s + 0];
    float py = qy + offwt[w][3 * s + 1];
    float pz = qz + offwt[w][3 * s + 2];
    wa0 += wt * bilerp(Tb, px, pz, lane);
    wa1 += wt * bilerp(Tb + PL_STRIDE, px, py, lane);
    wa2 += wt * bilerp(Tb + 2 * PL_STRIDE, py, pz, lane);
    swt += wt;
  }

  size_t o = (size_t)p * IN_DIM + lane;
  waux[o] = wa0; waux[o + 64] = wa1; waux[o + 128] = wa2;
  if (lane == 0) swtg[p] = swt;
  featg[o] = f0; featg[o + 64] = f1; featg[o + 128] = f2;
}

// ---------------------------------------------------------------------------
// Kernel 4: out = waux @ Wc^T + swt*bc + b_out + feature (feature lives in out).
// 8 waves/block share 48KB LDS chunks of WcT; each wave owns 4 points;
// waux row reads are wave-uniform (readfirstlane) -> scalar s_load path.
// ---------------------------------------------------------------------------
__global__ __launch_bounds__(512) void out_gemm(
    const float* __restrict__ waux, const float* __restrict__ swtg,
    const float* __restrict__ WcT, const float* __restrict__ bc,
    const float* __restrict__ b_out, float* __restrict__ out) {
  __shared__ float wtile[64 * IN_DIM];  // 48KB: rows k0..k0+63 of WcT
  int tid = threadIdx.x;
  int w = tid >> 6, lane = tid & 63;
  int pbase = blockIdx.x * 32 + w * 4;

  const float* wrow[4];
#pragma unroll
  for (int q = 0; q < 4; ++q)
    wrow[q] = waux + (size_t)__builtin_amdgcn_readfirstlane(pbase + q) * IN_DIM;

  float acc[4][3] = {};
  for (int c = 0; c < 3; ++c) {
#pragma unroll
    for (int r = 0; r < 24; ++r)
      wtile[tid + r * 512] = WcT[c * 64 * IN_DIM + tid + r * 512];
    __syncthreads();
#pragma unroll 2
    for (int k = 0; k < 64; ++k) {
      float v0 = wtile[k * IN_DIM + lane];
      float v1 = wtile[k * IN_DIM + 64 + lane];
      float v2 = wtile[k * IN_DIM + 128 + lane];
#pragma unroll
      for (int q = 0; q < 4; ++q) {
        float wv = wrow[q][c * 64 + k];
        acc[q][0] += v0 * wv;
        acc[q][1] += v1 * wv;
        acc[q][2] += v2 * wv;
      }
    }
    __syncthreads();
  }
#pragma unroll
  for (int q = 0; q < 4; ++q) {
    int p = pbase + q;
    float sw = swtg[p];
#pragma unroll
    for (int t = 0; t < 3; ++t) {
      int j = lane + t * 64;
      size_t o = (size_t)p * IN_DIM + j;
      out[o] = acc[q][t] + sw * bc[j] + b_out[j] + out[o];
    }
  }
}

// ---------------------------------------------------------------------------
extern "C" void kernel_launch(void* const* d_in, const int* in_sizes, int n_in,
                              void* d_out, int out_size, void* d_ws,
                              size_t ws_size, hipStream_t stream) {
  const float* qpos  = (const float*)d_in[0];
  const float* xz    = (const float*)d_in[1];
  const float* xy    = (const float*)d_in[2];
  const float* yz    = (const float*)d_in[3];
  const float* W_v   = (const float*)d_in[4];
  const float* b_v   = (const float*)d_in[5];
  const float* W_out = (const float*)d_in[6];
  const float* b_out = (const float*)d_in[7];
  const float* W_off = (const float*)d_in[8];
  const float* b_off = (const float*)d_in[9];
  const float* W_wt  = (const float*)d_in[10];
  const float* b_wt  = (const float*)d_in[11];

  float* ws      = (float*)d_ws;
  float* planesT = ws;                                   // 12.58M floats
  float* waux    = planesT + PLANES_T_FLOATS;            // 12.58M floats
  float* swtg    = waux + (size_t)NPTS * IN_DIM;         // 65536
  float* WcT     = swtg + NPTS;                          // 36864
  float* bc      = WcT + IN_DIM * IN_DIM;                // 192
  float* out     = (float*)d_out;
  // total ws need: ~96.4 MiB

  hipLaunchKernelGGL(transpose_planes, dim3(BS * 3 * RES * 4), dim3(256), 0,
                     stream, xz, xy, yz, planesT);
  hipLaunchKernelGGL(precompute_wc, dim3(IN_DIM + 1), dim3(IN_DIM), 0, stream,
                     W_v, b_v, W_out, WcT, bc);
  hipLaunchKernelGGL(fused_sample, dim3(NPTS / 4), dim3(256), 0, stream, qpos,
                     planesT, W_off, b_off, W_wt, b_wt, waux, swtg, out);
  hipLaunchKernelGGL(out_gemm, dim3(NPTS / 32), dim3(512), 0, stream, waux,
                     swtg, WcT, bc, b_out, out);
}

// Round 3
// 484.552 us; speedup vs baseline: 1.0644x; 1.0644x over previous
//
#include <hip/hip_runtime.h>

#define BS 4
#define NS 16384
#define S_SAMP 8
#define CPL 64
#define RES 128
#define IN_DIM 192
#define NPTS (BS * NS)                 // 65536
#define PL_STRIDE (RES * RES * CPL)    // 1048576 floats per (batch,plane)
#define PLANES_T_FLOATS (BS * 3 * PL_STRIDE)

// ---------------------------------------------------------------------------
// Kernel 1: transpose planes [B,C,H,W] -> [B,pl,H,W,C] so channel gathers are
// coalesced 256B wave loads (lane = channel).
// ---------------------------------------------------------------------------
__global__ __launch_bounds__(256) void transpose_planes(
    const float* __restrict__ xz, const float* __restrict__ xy,
    const float* __restrict__ yz, float* __restrict__ T) {
  __shared__ float tile[64][33];  // +1 pad: conflict-free both phases
  int blk = blockIdx.x;
  int xt = blk & 3;             // x-tile (32 wide)
  int y  = (blk >> 2) & 127;
  int pl = (blk >> 9) % 3;
  int b  = blk / 1536;
  const float* src = (pl == 0) ? xz : ((pl == 1) ? xy : yz);
  src += (size_t)b * CPL * RES * RES + (size_t)y * RES + xt * 32;
  int tid = threadIdx.x;
  int xl = tid & 31, c0 = tid >> 5;
#pragma unroll
  for (int r = 0; r < 8; ++r) {
    int c = c0 + (r << 3);
    tile[c][xl] = src[(size_t)c * RES * RES + xl];  // coalesced over xl
  }
  __syncthreads();
  float* dst = T + ((size_t)(b * 3 + pl) * RES * RES + (size_t)y * RES + xt * 32) * CPL;
  int c2 = tid & 63, x0 = tid >> 6;
#pragma unroll
  for (int r = 0; r < 8; ++r) {
    int xl2 = x0 + (r << 2);
    dst[(size_t)xl2 * CPL + c2] = tile[c2][xl2];    // coalesced over c2
  }
}

// ---------------------------------------------------------------------------
// Kernel 2: fold W_out@W_v -> WcT ([k][j] layout), bc = W_out@b_v
// ---------------------------------------------------------------------------
__global__ __launch_bounds__(192) void precompute_wc(
    const float* __restrict__ W_v, const float* __restrict__ b_v,
    const float* __restrict__ W_out, float* __restrict__ WcT,
    float* __restrict__ bc) {
  int j = threadIdx.x;
  int k = blockIdx.x;
  if (k < IN_DIM) {
    float acc = 0.f;
    for (int m = 0; m < IN_DIM; ++m)
      acc += W_out[j * IN_DIM + m] * W_v[m * IN_DIM + k];
    WcT[k * IN_DIM + j] = acc;  // WcT[k][j] = Wc[j][k]
  } else {
    float acc = 0.f;
    for (int m = 0; m < IN_DIM; ++m)
      acc += W_out[j * IN_DIM + m] * b_v[m];
    bc[j] = acc;
  }
}

// ---------------------------------------------------------------------------
// Bilinear sample with SCALAR addressing: u,v are wave-uniform; readfirstlane
// moves x0/y0 to SGPRs so the 4 tap addresses are SALU (s[base] + lane*4).
// Per bilerp: ~6 VALU lerp + ~8 VALU uv math instead of ~40 VALU.
// ---------------------------------------------------------------------------
__device__ __forceinline__ float bilerp_s(const float* __restrict__ pb, float u,
                                          float v, int lane) {
  u = fminf(fmaxf(u, 0.f), 1.f) * 127.f;
  v = fminf(fmaxf(v, 0.f), 1.f) * 127.f;
  float xf = floorf(u), yf = floorf(v);
  float wx = u - xf, wy = v - yf;
  int x0 = __builtin_amdgcn_readfirstlane((int)xf);
  int y0 = __builtin_amdgcn_readfirstlane((int)yf);
  int dx = (x0 < 127) ? CPL : 0;          // (x1-x0)*CPL, scalar
  int dy = (y0 < 127) ? RES * CPL : 0;    // (y1-y0)*RES*CPL, scalar
  const float* b00 = pb + (((y0 << 7) + x0) << 6);
  float f00 = b00[lane];
  float f01 = b00[dx + lane];
  float f10 = b00[dy + lane];
  float f11 = b00[dy + dx + lane];
  float fx0 = f00 + wx * (f01 - f00);
  float fx1 = f10 + wx * (f11 - f10);
  return fx0 + wy * (fx1 - fx0);
}

// ---------------------------------------------------------------------------
// Kernel 3: one wave per query point.
//   feature (12 taps) -> LDS -> off/wt matvec (all 64 lanes, split-k + shfl) ->
//   8 aux samples (96 taps, unroll-4 for MLP) -> waux, swt.
// feature goes straight into d_out (residual term).
// ---------------------------------------------------------------------------
__global__ __launch_bounds__(256, 4) void fused_sample(
    const float* __restrict__ qpos, const float* __restrict__ planesT,
    const float* __restrict__ W_off, const float* __restrict__ b_off,
    const float* __restrict__ W_wt, const float* __restrict__ b_wt,
    float* __restrict__ waux, float* __restrict__ swtg,
    float* __restrict__ featg) {
  __shared__ float feat_lds[4][IN_DIM];
  __shared__ float offwt[4][32];  // 0..23 = off, 24..31 = wt
  int w = threadIdx.x >> 6, lane = threadIdx.x & 63;
  int p = (blockIdx.x << 2) + w;
  int b = p >> 14;  // NS = 16384 points per batch
  float qx = qpos[p * 3 + 0], qy = qpos[p * 3 + 1], qz = qpos[p * 3 + 2];
  const float* Tb = planesT + (size_t)b * 3 * PL_STRIDE;

  float f0 = bilerp_s(Tb, qx, qz, lane);                  // xz: (x,z)
  float f1 = bilerp_s(Tb + PL_STRIDE, qx, qy, lane);      // xy: (x,y)
  float f2 = bilerp_s(Tb + 2 * PL_STRIDE, qy, qz, lane);  // yz: (y,z)
  feat_lds[w][lane] = f0;
  feat_lds[w][64 + lane] = f1;
  feat_lds[w][128 + lane] = f2;
  __syncthreads();

  {  // matvec: 32 outputs, each computed by 2 lanes over half the k range
    int oj = lane & 31;
    const float* row = (oj < 24) ? (W_off + oj * IN_DIM)
                                 : (W_wt + (oj - 24) * IN_DIM);
    float bias = (oj < 24) ? b_off[oj] : b_wt[oj - 24];
    int k0 = (lane >> 5) * 96;
    const float4* r4 = (const float4*)(row + k0);
    float a0 = 0.f, a1 = 0.f, a2 = 0.f, a3 = 0.f;
#pragma unroll
    for (int k4 = 0; k4 < 24; ++k4) {
      float4 rv = r4[k4];
      a0 += rv.x * feat_lds[w][k0 + 4 * k4 + 0];
      a1 += rv.y * feat_lds[w][k0 + 4 * k4 + 1];
      a2 += rv.z * feat_lds[w][k0 + 4 * k4 + 2];
      a3 += rv.w * feat_lds[w][k0 + 4 * k4 + 3];
    }
    float acc = (a0 + a1) + (a2 + a3);
    acc += __shfl_xor(acc, 32);
    if (lane < 32) offwt[w][oj] = acc + bias;
  }
  __syncthreads();

  float wa0 = 0.f, wa1 = 0.f, wa2 = 0.f, swt = 0.f;
#pragma unroll 4
  for (int s = 0; s < S_SAMP; ++s) {
    float wt = offwt[w][24 + s];
    float px = qx + offwt[w][3 * s + 0];
    float py = qy + offwt[w][3 * s + 1];
    float pz = qz + offwt[w][3 * s + 2];
    wa0 += wt * bilerp_s(Tb, px, pz, lane);
    wa1 += wt * bilerp_s(Tb + PL_STRIDE, px, py, lane);
    wa2 += wt * bilerp_s(Tb + 2 * PL_STRIDE, py, pz, lane);
    swt += wt;
  }

  size_t o = (size_t)p * IN_DIM + lane;
  waux[o] = wa0; waux[o + 64] = wa1; waux[o + 128] = wa2;
  if (lane == 0) swtg[p] = swt;
  featg[o] = f0; featg[o + 64] = f1; featg[o + 128] = f2;
}

// ---------------------------------------------------------------------------
// Kernel 4: out = waux @ Wc^T + swt*bc + b_out + feature (feature lives in out).
// 512 blocks x 512 thr; block owns 128 points; WcT staged in 3 x 48KB chunks,
// each staged ONCE per block (74 MB total L2 traffic vs 295 MB before).
// Accumulators (48/lane) live across chunks. waux rows via scalar s_loads.
// ---------------------------------------------------------------------------
__global__ __launch_bounds__(512) void out_gemm(
    const float* __restrict__ waux, const float* __restrict__ swtg,
    const float* __restrict__ WcT, const float* __restrict__ bc,
    const float* __restrict__ b_out, float* __restrict__ out) {
  __shared__ float wtile[64 * IN_DIM];  // 48KB: k rows [k][j]
  int tid = threadIdx.x;
  int w = tid >> 6, lane = tid & 63;
  int p0 = blockIdx.x * 128 + w * 16;   // 16 points per wave

  float acc[4][4][3] = {};              // [group][pt][t]
  for (int c = 0; c < 3; ++c) {
#pragma unroll
    for (int r = 0; r < 24; ++r)
      wtile[tid + r * 512] = WcT[c * 64 * IN_DIM + tid + r * 512];
    __syncthreads();
#pragma unroll
    for (int g = 0; g < 4; ++g) {
      const float* wrow[4];
#pragma unroll
      for (int q = 0; q < 4; ++q)
        wrow[q] = waux +
                  (size_t)__builtin_amdgcn_readfirstlane(p0 + g * 4 + q) * IN_DIM +
                  c * 64;
#pragma unroll 4
      for (int k = 0; k < 64; ++k) {
        float v0 = wtile[k * IN_DIM + lane];
        float v1 = wtile[k * IN_DIM + 64 + lane];
        float v2 = wtile[k * IN_DIM + 128 + lane];
#pragma unroll
        for (int q = 0; q < 4; ++q) {
          float wv = wrow[q][k];
          acc[g][q][0] += v0 * wv;
          acc[g][q][1] += v1 * wv;
          acc[g][q][2] += v2 * wv;
        }
      }
    }
    __syncthreads();
  }
#pragma unroll
  for (int g = 0; g < 4; ++g)
#pragma unroll
    for (int q = 0; q < 4; ++q) {
      int p = p0 + g * 4 + q;
      float sw = swtg[p];
#pragma unroll
      for (int t = 0; t < 3; ++t) {
        int j = lane + t * 64;
        size_t o = (size_t)p * IN_DIM + j;
        out[o] = acc[g][q][t] + sw * bc[j] + b_out[j] + out[o];
      }
    }
}

// ---------------------------------------------------------------------------
extern "C" void kernel_launch(void* const* d_in, const int* in_sizes, int n_in,
                              void* d_out, int out_size, void* d_ws,
                              size_t ws_size, hipStream_t stream) {
  const float* qpos  = (const float*)d_in[0];
  const float* xz    = (const float*)d_in[1];
  const float* xy    = (const float*)d_in[2];
  const float* yz    = (const float*)d_in[3];
  const float* W_v   = (const float*)d_in[4];
  const float* b_v   = (const float*)d_in[5];
  const float* W_out = (const float*)d_in[6];
  const float* b_out = (const float*)d_in[7];
  const float* W_off = (const float*)d_in[8];
  const float* b_off = (const float*)d_in[9];
  const float* W_wt  = (const float*)d_in[10];
  const float* b_wt  = (const float*)d_in[11];

  float* ws      = (float*)d_ws;
  float* planesT = ws;                                   // 12.58M floats
  float* waux    = planesT + PLANES_T_FLOATS;            // 12.58M floats
  float* swtg    = waux + (size_t)NPTS * IN_DIM;         // 65536
  float* WcT     = swtg + NPTS;                          // 36864
  float* bc      = WcT + IN_DIM * IN_DIM;                // 192
  float* out     = (float*)d_out;
  // total ws need: ~96.4 MiB

  hipLaunchKernelGGL(transpose_planes, dim3(BS * 3 * RES * 4), dim3(256), 0,
                     stream, xz, xy, yz, planesT);
  hipLaunchKernelGGL(precompute_wc, dim3(IN_DIM + 1), dim3(IN_DIM), 0, stream,
                     W_v, b_v, W_out, WcT, bc);
  hipLaunchKernelGGL(fused_sample, dim3(NPTS / 4), dim3(256), 0, stream, qpos,
                     planesT, W_off, b_off, W_wt, b_wt, waux, swtg, out);
  hipLaunchKernelGGL(out_gemm, dim3(NPTS / 128), dim3(512), 0, stream, waux,
                     swtg, WcT, bc, b_out, out);
}

// Round 4
// 482.244 us; speedup vs baseline: 1.0695x; 1.0048x over previous
//
#include <hip/hip_runtime.h>

#define BS 4
#define NS 16384
#define S_SAMP 8
#define CPL 64
#define RES 128
#define IN_DIM 192
#define NPTS (BS * NS)                 // 65536
#define PL_STRIDE (RES * RES * CPL)    // 1048576 floats per (batch,plane)
#define PLANES_T_FLOATS (BS * 3 * PL_STRIDE)

// ---------------------------------------------------------------------------
// Kernel 1: transpose planes [B,C,H,W] -> [B,pl,H,W,C] so channel gathers are
// coalesced 256B wave loads (lane = channel).
// ---------------------------------------------------------------------------
__global__ __launch_bounds__(256) void transpose_planes(
    const float* __restrict__ xz, const float* __restrict__ xy,
    const float* __restrict__ yz, float* __restrict__ T) {
  __shared__ float tile[64][33];
  int blk = blockIdx.x;
  int xt = blk & 3;
  int y  = (blk >> 2) & 127;
  int pl = (blk >> 9) % 3;
  int b  = blk / 1536;
  const float* src = (pl == 0) ? xz : ((pl == 1) ? xy : yz);
  src += (size_t)b * CPL * RES * RES + (size_t)y * RES + xt * 32;
  int tid = threadIdx.x;
  int xl = tid & 31, c0 = tid >> 5;
#pragma unroll
  for (int r = 0; r < 8; ++r) {
    int c = c0 + (r << 3);
    tile[c][xl] = src[(size_t)c * RES * RES + xl];
  }
  __syncthreads();
  float* dst = T + ((size_t)(b * 3 + pl) * RES * RES + (size_t)y * RES + xt * 32) * CPL;
  int c2 = tid & 63, x0 = tid >> 6;
#pragma unroll
  for (int r = 0; r < 8; ++r) {
    int xl2 = x0 + (r << 2);
    dst[(size_t)xl2 * CPL + c2] = tile[c2][xl2];
  }
}

// ---------------------------------------------------------------------------
// Kernel 2: Wc = W_out @ W_v (WcT[k][j] layout), bc = W_out @ b_v.
// k = tid (coalesced W_v loads), j = block (uniform W_out s_loads).
// ---------------------------------------------------------------------------
__global__ __launch_bounds__(192) void precompute_wc(
    const float* __restrict__ W_v, const float* __restrict__ b_v,
    const float* __restrict__ W_out, float* __restrict__ WcT,
    float* __restrict__ bc) {
  int j = blockIdx.x;
  int k = threadIdx.x;
  if (j < IN_DIM) {
    float acc = 0.f;
    for (int m = 0; m < IN_DIM; ++m)
      acc += W_out[j * IN_DIM + m] * W_v[m * IN_DIM + k];  // uniform * coalesced
    WcT[k * IN_DIM + j] = acc;
  } else {
    float acc = 0.f;
    for (int m = 0; m < IN_DIM; ++m)
      acc += W_out[k * IN_DIM + m] * b_v[m];  // k plays the j role here
    bc[k] = acc;
  }
}

// ---------------------------------------------------------------------------
// Tap-address helper: u,v wave-uniform -> scalar base (SGPR) + scalar dx/dy.
// ---------------------------------------------------------------------------
__device__ __forceinline__ void mkaddr(const float* __restrict__ pb, float u,
                                       float v, const float*& b00, int& dx,
                                       int& dy, float& wx, float& wy) {
  u = fminf(fmaxf(u, 0.f), 1.f) * 127.f;
  v = fminf(fmaxf(v, 0.f), 1.f) * 127.f;
  float xf = floorf(u), yf = floorf(v);
  wx = u - xf;
  wy = v - yf;
  int x0 = __builtin_amdgcn_readfirstlane((int)xf);
  int y0 = __builtin_amdgcn_readfirstlane((int)yf);
  dx = (x0 < 127) ? CPL : 0;
  dy = (y0 < 127) ? RES * CPL : 0;
  b00 = pb + (((y0 << 7) + x0) << 6);
}

// ---------------------------------------------------------------------------
// Kernel 3: one wave per TWO query points (pair ILP). Tap loads batched in
// groups of 6 bilerps (24 loads issued before any lerp math) for MLP.
// ---------------------------------------------------------------------------
__global__ __launch_bounds__(256, 4) void fused_sample(
    const float* __restrict__ qpos, const float* __restrict__ planesT,
    const float* __restrict__ W_off, const float* __restrict__ b_off,
    const float* __restrict__ W_wt, const float* __restrict__ b_wt,
    float* __restrict__ waux, float* __restrict__ swtg,
    float* __restrict__ featg) {
  __shared__ float feat_lds[8][IN_DIM];
  __shared__ float offwt[8][32];  // 0..23 = off, 24..31 = wt
  int w = threadIdx.x >> 6, lane = threadIdx.x & 63;
  int p0 = blockIdx.x * 8 + w * 2;
  int p1 = p0 + 1;
  int b0 = p0 >> 14, b1 = p1 >> 14;
  float qx0 = qpos[p0 * 3 + 0], qy0 = qpos[p0 * 3 + 1], qz0 = qpos[p0 * 3 + 2];
  float qx1 = qpos[p1 * 3 + 0], qy1 = qpos[p1 * 3 + 1], qz1 = qpos[p1 * 3 + 2];
  const float* Tb0 = planesT + (size_t)b0 * 3 * PL_STRIDE;
  const float* Tb1 = planesT + (size_t)b1 * 3 * PL_STRIDE;

  // ---- Phase A: feature bilerps, batched (6 bilerps, 24 loads in flight)
  float f[6];
  {
    const float* B[6]; int DX[6], DY[6]; float WX[6], WY[6];
    mkaddr(Tb0,                 qx0, qz0, B[0], DX[0], DY[0], WX[0], WY[0]);
    mkaddr(Tb0 + PL_STRIDE,     qx0, qy0, B[1], DX[1], DY[1], WX[1], WY[1]);
    mkaddr(Tb0 + 2 * PL_STRIDE, qy0, qz0, B[2], DX[2], DY[2], WX[2], WY[2]);
    mkaddr(Tb1,                 qx1, qz1, B[3], DX[3], DY[3], WX[3], WY[3]);
    mkaddr(Tb1 + PL_STRIDE,     qx1, qy1, B[4], DX[4], DY[4], WX[4], WY[4]);
    mkaddr(Tb1 + 2 * PL_STRIDE, qy1, qz1, B[5], DX[5], DY[5], WX[5], WY[5]);
    float t00[6], t01[6], t10[6], t11[6];
#pragma unroll
    for (int i = 0; i < 6; ++i) {
      t00[i] = B[i][lane];
      t01[i] = B[i][DX[i] + lane];
      t10[i] = B[i][DY[i] + lane];
      t11[i] = B[i][DY[i] + DX[i] + lane];
    }
#pragma unroll
    for (int i = 0; i < 6; ++i) {
      float a = t00[i] + WX[i] * (t01[i] - t00[i]);
      float c = t10[i] + WX[i] * (t11[i] - t10[i]);
      f[i] = a + WY[i] * (c - a);
    }
  }
  feat_lds[w * 2 + 0][lane] = f[0];
  feat_lds[w * 2 + 0][64 + lane] = f[1];
  feat_lds[w * 2 + 0][128 + lane] = f[2];
  feat_lds[w * 2 + 1][lane] = f[3];
  feat_lds[w * 2 + 1][64 + lane] = f[4];
  feat_lds[w * 2 + 1][128 + lane] = f[5];
  __syncthreads();

  // ---- Matvec: 64 tasks = 2 points x 32 outputs; lane owns one full row.
  {
    int pt = lane >> 5, oj = lane & 31;
    const float* row = (oj < 24) ? (W_off + oj * IN_DIM)
                                 : (W_wt + (oj - 24) * IN_DIM);
    float bias = (oj < 24) ? b_off[oj] : b_wt[oj - 24];
    const float4* r4 = (const float4*)row;
    const float4* fl = (const float4*)feat_lds[w * 2 + pt];
    float a0 = 0.f, a1 = 0.f, a2 = 0.f, a3 = 0.f;
#pragma unroll
    for (int k4 = 0; k4 < IN_DIM / 4; ++k4) {
      float4 rv = r4[k4];
      float4 fv = fl[k4];
      a0 += rv.x * fv.x;
      a1 += rv.y * fv.y;
      a2 += rv.z * fv.z;
      a3 += rv.w * fv.w;
    }
    offwt[w * 2 + pt][oj] = bias + ((a0 + a1) + (a2 + a3));
  }
  __syncthreads();

  // ---- Phase C: 8 samples x 2 points x 3 planes, batched per s (24 loads).
  float wa[2][3] = {};
  float swt0 = 0.f, swt1 = 0.f;
#pragma unroll 2
  for (int s = 0; s < S_SAMP; ++s) {
    float ox0 = offwt[w * 2 + 0][3 * s + 0];
    float oy0 = offwt[w * 2 + 0][3 * s + 1];
    float oz0 = offwt[w * 2 + 0][3 * s + 2];
    float wt0 = offwt[w * 2 + 0][24 + s];
    float ox1 = offwt[w * 2 + 1][3 * s + 0];
    float oy1 = offwt[w * 2 + 1][3 * s + 1];
    float oz1 = offwt[w * 2 + 1][3 * s + 2];
    float wt1 = offwt[w * 2 + 1][24 + s];
    float px0 = qx0 + ox0, py0 = qy0 + oy0, pz0 = qz0 + oz0;
    float px1 = qx1 + ox1, py1 = qy1 + oy1, pz1 = qz1 + oz1;

    const float* B[6]; int DX[6], DY[6]; float WX[6], WY[6];
    mkaddr(Tb0,                 px0, pz0, B[0], DX[0], DY[0], WX[0], WY[0]);
    mkaddr(Tb0 + PL_STRIDE,     px0, py0, B[1], DX[1], DY[1], WX[1], WY[1]);
    mkaddr(Tb0 + 2 * PL_STRIDE, py0, pz0, B[2], DX[2], DY[2], WX[2], WY[2]);
    mkaddr(Tb1,                 px1, pz1, B[3], DX[3], DY[3], WX[3], WY[3]);
    mkaddr(Tb1 + PL_STRIDE,     px1, py1, B[4], DX[4], DY[4], WX[4], WY[4]);
    mkaddr(Tb1 + 2 * PL_STRIDE, py1, pz1, B[5], DX[5], DY[5], WX[5], WY[5]);
    float t00[6], t01[6], t10[6], t11[6];
#pragma unroll
    for (int i = 0; i < 6; ++i) {
      t00[i] = B[i][lane];
      t01[i] = B[i][DX[i] + lane];
      t10[i] = B[i][DY[i] + lane];
      t11[i] = B[i][DY[i] + DX[i] + lane];
    }
    float r[6];
#pragma unroll
    for (int i = 0; i < 6; ++i) {
      float a = t00[i] + WX[i] * (t01[i] - t00[i]);
      float c = t10[i] + WX[i] * (t11[i] - t10[i]);
      r[i] = a + WY[i] * (c - a);
    }
    wa[0][0] += wt0 * r[0]; wa[0][1] += wt0 * r[1]; wa[0][2] += wt0 * r[2];
    wa[1][0] += wt1 * r[3]; wa[1][1] += wt1 * r[4]; wa[1][2] += wt1 * r[5];
    swt0 += wt0; swt1 += wt1;
  }

  size_t o0 = (size_t)p0 * IN_DIM + lane;
  size_t o1 = (size_t)p1 * IN_DIM + lane;
  waux[o0] = wa[0][0]; waux[o0 + 64] = wa[0][1]; waux[o0 + 128] = wa[0][2];
  waux[o1] = wa[1][0]; waux[o1 + 64] = wa[1][1]; waux[o1 + 128] = wa[1][2];
  if (lane == 0) { swtg[p0] = swt0; swtg[p1] = swt1; }
  featg[o0] = f[0]; featg[o0 + 64] = f[1]; featg[o0 + 128] = f[2];
  featg[o1] = f[3]; featg[o1 + 64] = f[4]; featg[o1 + 128] = f[5];
}

// ---------------------------------------------------------------------------
// Kernel 4: out = waux @ Wc^T + swt*bc + b_out + feature (feature lives in out).
// Block = 256 thr, owns 64 points. waux tile staged in LDS via coalesced
// float4 VECTOR loads (no scalar-cache abuse); per-(p,k4) broadcast
// ds_read_b128; WcT rows read from L2 with vector loads (144KB, L2-hot).
// ---------------------------------------------------------------------------
__global__ __launch_bounds__(256) void out_gemm(
    const float* __restrict__ waux, const float* __restrict__ swtg,
    const float* __restrict__ WcT, const float* __restrict__ bc,
    const float* __restrict__ b_out, float* __restrict__ out) {
  __shared__ float at[64 * IN_DIM];  // 48KB waux tile
  int tid = threadIdx.x;
  int w = tid >> 6, lane = tid & 63;
  int p0 = blockIdx.x * 64;

  const float4* src = (const float4*)(waux + (size_t)p0 * IN_DIM);
  float4* dst4 = (float4*)at;
#pragma unroll
  for (int i = 0; i < 12; ++i) dst4[tid + i * 256] = src[tid + i * 256];
  __syncthreads();

  int pw = w * 16;  // this wave's 16 rows of the tile
  float acc[16][3] = {};
  for (int c = 0; c < 3; ++c) {
    const float* wc = WcT + c * 64 * IN_DIM;
#pragma unroll 2
    for (int k4 = 0; k4 < 16; ++k4) {
      float v0[4], v1[4], v2[4];
#pragma unroll
      for (int kk = 0; kk < 4; ++kk) {
        const float* r = wc + (k4 * 4 + kk) * IN_DIM;
        v0[kk] = r[lane];
        v1[kk] = r[64 + lane];
        v2[kk] = r[128 + lane];
      }
#pragma unroll
      for (int q = 0; q < 16; ++q) {
        float4 a4 = *(const float4*)&at[(pw + q) * IN_DIM + c * 64 + k4 * 4];
        acc[q][0] += v0[0] * a4.x + v0[1] * a4.y + v0[2] * a4.z + v0[3] * a4.w;
        acc[q][1] += v1[0] * a4.x + v1[1] * a4.y + v1[2] * a4.z + v1[3] * a4.w;
        acc[q][2] += v2[0] * a4.x + v2[1] * a4.y + v2[2] * a4.z + v2[3] * a4.w;
      }
    }
  }

  float bcv[3], bov[3];
#pragma unroll
  for (int t = 0; t < 3; ++t) {
    bcv[t] = bc[lane + t * 64];
    bov[t] = b_out[lane + t * 64];
  }
#pragma unroll
  for (int q = 0; q < 16; ++q) {
    int p = p0 + pw + q;
    float sw = swtg[p];
#pragma unroll
    for (int t = 0; t < 3; ++t) {
      size_t o = (size_t)p * IN_DIM + lane + t * 64;
      out[o] = acc[q][t] + sw * bcv[t] + bov[t] + out[o];
    }
  }
}

// ---------------------------------------------------------------------------
extern "C" void kernel_launch(void* const* d_in, const int* in_sizes, int n_in,
                              void* d_out, int out_size, void* d_ws,
                              size_t ws_size, hipStream_t stream) {
  const float* qpos  = (const float*)d_in[0];
  const float* xz    = (const float*)d_in[1];
  const float* xy    = (const float*)d_in[2];
  const float* yz    = (const float*)d_in[3];
  const float* W_v   = (const float*)d_in[4];
  const float* b_v   = (const float*)d_in[5];
  const float* W_out = (const float*)d_in[6];
  const float* b_out = (const float*)d_in[7];
  const float* W_off = (const float*)d_in[8];
  const float* b_off = (const float*)d_in[9];
  const float* W_wt  = (const float*)d_in[10];
  const float* b_wt  = (const float*)d_in[11];

  float* ws      = (float*)d_ws;
  float* planesT = ws;
  float* waux    = planesT + PLANES_T_FLOATS;
  float* swtg    = waux + (size_t)NPTS * IN_DIM;
  float* WcT     = swtg + NPTS;
  float* bc      = WcT + IN_DIM * IN_DIM;
  float* out     = (float*)d_out;

  hipLaunchKernelGGL(transpose_planes, dim3(BS * 3 * RES * 4), dim3(256), 0,
                     stream, xz, xy, yz, planesT);
  hipLaunchKernelGGL(precompute_wc, dim3(IN_DIM + 1), dim3(IN_DIM), 0, stream,
                     W_v, b_v, W_out, WcT, bc);
  hipLaunchKernelGGL(fused_sample, dim3(NPTS / 8), dim3(256), 0, stream, qpos,
                     planesT, W_off, b_off, W_wt, b_wt, waux, swtg, out);
  hipLaunchKernelGGL(out_gemm, dim3(NPTS / 64), dim3(256), 0, stream, waux,
                     swtg, WcT, bc, b_out, out);
}

// Round 5
// 470.085 us; speedup vs baseline: 1.0972x; 1.0259x over previous
//
#include <hip/hip_runtime.h>

#define BS 4
#define NS 16384
#define S_SAMP 8
#define CPL 64
#define RES 128
#define IN_DIM 192
#define NPTS (BS * NS)                 // 65536
#define PL_STRIDE (RES * RES * CPL)    // 1048576 floats per (batch,plane)
#define PLANES_T_FLOATS (BS * 3 * PL_STRIDE)

// ---------------------------------------------------------------------------
// Kernel 1: transpose planes [B,C,H,W] -> [B,pl,H,W,C].
// ---------------------------------------------------------------------------
__global__ __launch_bounds__(256) void transpose_planes(
    const float* __restrict__ xz, const float* __restrict__ xy,
    const float* __restrict__ yz, float* __restrict__ T) {
  __shared__ float tile[64][33];
  int blk = blockIdx.x;
  int xt = blk & 3;
  int y  = (blk >> 2) & 127;
  int pl = (blk >> 9) % 3;
  int b  = blk / 1536;
  const float* src = (pl == 0) ? xz : ((pl == 1) ? xy : yz);
  src += (size_t)b * CPL * RES * RES + (size_t)y * RES + xt * 32;
  int tid = threadIdx.x;
  int xl = tid & 31, c0 = tid >> 5;
#pragma unroll
  for (int r = 0; r < 8; ++r) {
    int c = c0 + (r << 3);
    tile[c][xl] = src[(size_t)c * RES * RES + xl];
  }
  __syncthreads();
  float* dst = T + ((size_t)(b * 3 + pl) * RES * RES + (size_t)y * RES + xt * 32) * CPL;
  int c2 = tid & 63, x0 = tid >> 6;
#pragma unroll
  for (int r = 0; r < 8; ++r) {
    int xl2 = x0 + (r << 2);
    dst[(size_t)xl2 * CPL + c2] = tile[c2][xl2];
  }
}

// ---------------------------------------------------------------------------
// Kernel 2: Wc = W_out @ W_v (WcT[k][j] layout), bc = W_out @ b_v.
// ---------------------------------------------------------------------------
__global__ __launch_bounds__(192) void precompute_wc(
    const float* __restrict__ W_v, const float* __restrict__ b_v,
    const float* __restrict__ W_out, float* __restrict__ WcT,
    float* __restrict__ bc) {
  int j = blockIdx.x;
  int k = threadIdx.x;
  if (j < IN_DIM) {
    float acc = 0.f;
    for (int m = 0; m < IN_DIM; ++m)
      acc += W_out[j * IN_DIM + m] * W_v[m * IN_DIM + k];
    WcT[k * IN_DIM + j] = acc;
  } else {
    float acc = 0.f;
    for (int m = 0; m < IN_DIM; ++m)
      acc += W_out[k * IN_DIM + m] * b_v[m];
    bc[k] = acc;
  }
}

// ---------------------------------------------------------------------------
// Tap-address helper: u,v wave-uniform -> scalar base (SGPR) + scalar dx/dy.
// ---------------------------------------------------------------------------
__device__ __forceinline__ void mkaddr(const float* __restrict__ pb, float u,
                                       float v, const float*& b00, int& dx,
                                       int& dy, float& wx, float& wy) {
  u = fminf(fmaxf(u, 0.f), 1.f) * 127.f;
  v = fminf(fmaxf(v, 0.f), 1.f) * 127.f;
  float xf = floorf(u), yf = floorf(v);
  wx = u - xf;
  wy = v - yf;
  int x0 = __builtin_amdgcn_readfirstlane((int)xf);
  int y0 = __builtin_amdgcn_readfirstlane((int)yf);
  dx = (x0 < 127) ? CPL : 0;
  dy = (y0 < 127) ? RES * CPL : 0;
  b00 = pb + (((y0 << 7) + x0) << 6);
}

// Tap buffer for one s-iteration (2 points x 3 planes). All access is via
// fully-unrolled constant indices -> stays in registers (no scratch).
struct Taps {
  float t00[6], t01[6], t10[6], t11[6];
  float wx[6], wy[6];
  float wt0, wt1;
};

__device__ __forceinline__ void load_taps(
    int s, const float* __restrict__ ow0, const float* __restrict__ ow1,
    float qx0, float qy0, float qz0, float qx1, float qy1, float qz1,
    const float* __restrict__ Tb0, const float* __restrict__ Tb1, int lane,
    Taps& T) {
  float px0 = qx0 + ow0[3 * s + 0];
  float py0 = qy0 + ow0[3 * s + 1];
  float pz0 = qz0 + ow0[3 * s + 2];
  T.wt0 = ow0[24 + s];
  float px1 = qx1 + ow1[3 * s + 0];
  float py1 = qy1 + ow1[3 * s + 1];
  float pz1 = qz1 + ow1[3 * s + 2];
  T.wt1 = ow1[24 + s];
  const float* B[6];
  int DX[6], DY[6];
  mkaddr(Tb0,                 px0, pz0, B[0], DX[0], DY[0], T.wx[0], T.wy[0]);
  mkaddr(Tb0 + PL_STRIDE,     px0, py0, B[1], DX[1], DY[1], T.wx[1], T.wy[1]);
  mkaddr(Tb0 + 2 * PL_STRIDE, py0, pz0, B[2], DX[2], DY[2], T.wx[2], T.wy[2]);
  mkaddr(Tb1,                 px1, pz1, B[3], DX[3], DY[3], T.wx[3], T.wy[3]);
  mkaddr(Tb1 + PL_STRIDE,     px1, py1, B[4], DX[4], DY[4], T.wx[4], T.wy[4]);
  mkaddr(Tb1 + 2 * PL_STRIDE, py1, pz1, B[5], DX[5], DY[5], T.wx[5], T.wy[5]);
#pragma unroll
  for (int i = 0; i < 6; ++i) {
    T.t00[i] = B[i][lane];
    T.t01[i] = B[i][DX[i] + lane];
    T.t10[i] = B[i][DY[i] + lane];
    T.t11[i] = B[i][DY[i] + DX[i] + lane];
  }
}

__device__ __forceinline__ void lerp_acc(const Taps& T, float wa[6],
                                         float& swt0, float& swt1) {
#pragma unroll
  for (int i = 0; i < 6; ++i) {
    float a = T.t00[i] + T.wx[i] * (T.t01[i] - T.t00[i]);
    float c = T.t10[i] + T.wx[i] * (T.t11[i] - T.t10[i]);
    float r = a + T.wy[i] * (c - a);
    wa[i] += ((i < 3) ? T.wt0 : T.wt1) * r;
  }
  swt0 += T.wt0;
  swt1 += T.wt1;
}

// ---------------------------------------------------------------------------
// Kernel 3: one wave per TWO points; phase C software-pipelined with two
// NAMED tap buffers so the 24 loads of s+1 are in flight during lerp of s.
// ---------------------------------------------------------------------------
__global__ __launch_bounds__(256, 4) void fused_sample(
    const float* __restrict__ qpos, const float* __restrict__ planesT,
    const float* __restrict__ W_off, const float* __restrict__ b_off,
    const float* __restrict__ W_wt, const float* __restrict__ b_wt,
    float* __restrict__ waux, float* __restrict__ swtg,
    float* __restrict__ featg) {
  __shared__ float feat_lds[8][IN_DIM];
  __shared__ float offwt[8][32];  // 0..23 = off, 24..31 = wt
  int w = threadIdx.x >> 6, lane = threadIdx.x & 63;
  int w2 = w * 2;
  int p0 = blockIdx.x * 8 + w2;
  int p1 = p0 + 1;
  int b0 = p0 >> 14, b1 = p1 >> 14;
  float qx0 = qpos[p0 * 3 + 0], qy0 = qpos[p0 * 3 + 1], qz0 = qpos[p0 * 3 + 2];
  float qx1 = qpos[p1 * 3 + 0], qy1 = qpos[p1 * 3 + 1], qz1 = qpos[p1 * 3 + 2];
  const float* Tb0 = planesT + (size_t)b0 * 3 * PL_STRIDE;
  const float* Tb1 = planesT + (size_t)b1 * 3 * PL_STRIDE;

  // ---- Phase A: 6 feature bilerps, batched (24 loads in flight)
  float f[6];
  {
    const float* B[6]; int DX[6], DY[6]; float WX[6], WY[6];
    mkaddr(Tb0,                 qx0, qz0, B[0], DX[0], DY[0], WX[0], WY[0]);
    mkaddr(Tb0 + PL_STRIDE,     qx0, qy0, B[1], DX[1], DY[1], WX[1], WY[1]);
    mkaddr(Tb0 + 2 * PL_STRIDE, qy0, qz0, B[2], DX[2], DY[2], WX[2], WY[2]);
    mkaddr(Tb1,                 qx1, qz1, B[3], DX[3], DY[3], WX[3], WY[3]);
    mkaddr(Tb1 + PL_STRIDE,     qx1, qy1, B[4], DX[4], DY[4], WX[4], WY[4]);
    mkaddr(Tb1 + 2 * PL_STRIDE, qy1, qz1, B[5], DX[5], DY[5], WX[5], WY[5]);
    float t00[6], t01[6], t10[6], t11[6];
#pragma unroll
    for (int i = 0; i < 6; ++i) {
      t00[i] = B[i][lane];
      t01[i] = B[i][DX[i] + lane];
      t10[i] = B[i][DY[i] + lane];
      t11[i] = B[i][DY[i] + DX[i] + lane];
    }
#pragma unroll
    for (int i = 0; i < 6; ++i) {
      float a = t00[i] + WX[i] * (t01[i] - t00[i]);
      float c = t10[i] + WX[i] * (t11[i] - t10[i]);
      f[i] = a + WY[i] * (c - a);
    }
  }
  feat_lds[w2 + 0][lane] = f[0];
  feat_lds[w2 + 0][64 + lane] = f[1];
  feat_lds[w2 + 0][128 + lane] = f[2];
  feat_lds[w2 + 1][lane] = f[3];
  feat_lds[w2 + 1][64 + lane] = f[4];
  feat_lds[w2 + 1][128 + lane] = f[5];
  __syncthreads();

  // ---- Matvec: 64 tasks = 2 points x 32 outputs; lane owns one full row.
  {
    int pt = lane >> 5, oj = lane & 31;
    const float* row = (oj < 24) ? (W_off + oj * IN_DIM)
                                 : (W_wt + (oj - 24) * IN_DIM);
    float bias = (oj < 24) ? b_off[oj] : b_wt[oj - 24];
    const float4* r4 = (const float4*)row;
    const float4* fl = (const float4*)feat_lds[w2 + pt];
    float a0 = 0.f, a1 = 0.f, a2 = 0.f, a3 = 0.f;
#pragma unroll
    for (int k4 = 0; k4 < IN_DIM / 4; ++k4) {
      float4 rv = r4[k4];
      float4 fv = fl[k4];
      a0 += rv.x * fv.x;
      a1 += rv.y * fv.y;
      a2 += rv.z * fv.z;
      a3 += rv.w * fv.w;
    }
    offwt[w2 + pt][oj] = bias + ((a0 + a1) + (a2 + a3));
  }
  __syncthreads();

  // ---- Phase C: software-pipelined over s with named double buffers.
  const float* ow0 = offwt[w2 + 0];
  const float* ow1 = offwt[w2 + 1];
  float wa[6] = {};  // [pt0:3 planes, pt1:3 planes]
  float swt0 = 0.f, swt1 = 0.f;
  Taps TA, TB;
  load_taps(0, ow0, ow1, qx0, qy0, qz0, qx1, qy1, qz1, Tb0, Tb1, lane, TA);
#pragma unroll
  for (int s = 0; s < S_SAMP; s += 2) {
    if (s + 1 < S_SAMP)
      load_taps(s + 1, ow0, ow1, qx0, qy0, qz0, qx1, qy1, qz1, Tb0, Tb1, lane, TB);
    lerp_acc(TA, wa, swt0, swt1);
    if (s + 2 < S_SAMP)
      load_taps(s + 2, ow0, ow1, qx0, qy0, qz0, qx1, qy1, qz1, Tb0, Tb1, lane, TA);
    lerp_acc(TB, wa, swt0, swt1);
  }

  size_t o0 = (size_t)p0 * IN_DIM + lane;
  size_t o1 = (size_t)p1 * IN_DIM + lane;
  waux[o0] = wa[0]; waux[o0 + 64] = wa[1]; waux[o0 + 128] = wa[2];
  waux[o1] = wa[3]; waux[o1 + 64] = wa[4]; waux[o1 + 128] = wa[5];
  if (lane == 0) { swtg[p0] = swt0; swtg[p1] = swt1; }
  featg[o0] = f[0]; featg[o0 + 64] = f[1]; featg[o0 + 128] = f[2];
  featg[o1] = f[3]; featg[o1 + 64] = f[4]; featg[o1 + 128] = f[5];
}

// ---------------------------------------------------------------------------
// Kernel 4: out = waux @ Wc^T + swt*bc + b_out + feature (feature in out).
// 32-point tile (24KB LDS -> 6 blocks/CU), ONE barrier, flat k-loop,
// ds_reads batched 8-wide into independent regs before their FMA groups.
// ---------------------------------------------------------------------------
__global__ __launch_bounds__(256) void out_gemm(
    const float* __restrict__ waux, const float* __restrict__ swtg,
    const float* __restrict__ WcT, const float* __restrict__ bc,
    const float* __restrict__ b_out, float* __restrict__ out) {
  __shared__ float at[32 * IN_DIM];  // 24KB waux tile
  int tid = threadIdx.x;
  int w = tid >> 6, lane = tid & 63;
  int p0 = blockIdx.x * 32;

  const float4* src = (const float4*)(waux + (size_t)p0 * IN_DIM);
  float4* dst4 = (float4*)at;
#pragma unroll
  for (int i = 0; i < 6; ++i) dst4[tid + i * 256] = src[tid + i * 256];
  __syncthreads();

  int pw = w * 8;  // this wave's 8 rows of the tile
  float acc[8][3] = {};
#pragma unroll 2
  for (int k4 = 0; k4 < 48; ++k4) {
    float v0[4], v1[4], v2[4];
#pragma unroll
    for (int kk = 0; kk < 4; ++kk) {
      const float* r = WcT + (k4 * 4 + kk) * IN_DIM;
      v0[kk] = r[lane];
      v1[kk] = r[64 + lane];
      v2[kk] = r[128 + lane];
    }
    float4 a[8];
#pragma unroll
    for (int q = 0; q < 8; ++q)
      a[q] = *(const float4*)&at[(pw + q) * IN_DIM + k4 * 4];
#pragma unroll
    for (int q = 0; q < 8; ++q) {
      acc[q][0] += v0[0] * a[q].x + v0[1] * a[q].y + v0[2] * a[q].z + v0[3] * a[q].w;
      acc[q][1] += v1[0] * a[q].x + v1[1] * a[q].y + v1[2] * a[q].z + v1[3] * a[q].w;
      acc[q][2] += v2[0] * a[q].x + v2[1] * a[q].y + v2[2] * a[q].z + v2[3] * a[q].w;
    }
  }

  float bcv[3], bov[3];
#pragma unroll
  for (int t = 0; t < 3; ++t) {
    bcv[t] = bc[lane + t * 64];
    bov[t] = b_out[lane + t * 64];
  }
#pragma unroll
  for (int q = 0; q < 8; ++q) {
    int p = p0 + pw + q;
    float sw = swtg[p];
#pragma unroll
    for (int t = 0; t < 3; ++t) {
      size_t o = (size_t)p * IN_DIM + lane + t * 64;
      out[o] = acc[q][t] + sw * bcv[t] + bov[t] + out[o];
    }
  }
}

// ---------------------------------------------------------------------------
extern "C" void kernel_launch(void* const* d_in, const int* in_sizes, int n_in,
                              void* d_out, int out_size, void* d_ws,
                              size_t ws_size, hipStream_t stream) {
  const float* qpos  = (const float*)d_in[0];
  const float* xz    = (const float*)d_in[1];
  const float* xy    = (const float*)d_in[2];
  const float* yz    = (const float*)d_in[3];
  const float* W_v   = (const float*)d_in[4];
  const float* b_v   = (const float*)d_in[5];
  const float* W_out = (const float*)d_in[6];
  const float* b_out = (const float*)d_in[7];
  const float* W_off = (const float*)d_in[8];
  const float* b_off = (const float*)d_in[9];
  const float* W_wt  = (const float*)d_in[10];
  const float* b_wt  = (const float*)d_in[11];

  float* ws      = (float*)d_ws;
  float* planesT = ws;
  float* waux    = planesT + PLANES_T_FLOATS;
  float* swtg    = waux + (size_t)NPTS * IN_DIM;
  float* WcT     = swtg + NPTS;
  float* bc      = WcT + IN_DIM * IN_DIM;
  float* out     = (float*)d_out;

  hipLaunchKernelGGL(transpose_planes, dim3(BS * 3 * RES * 4), dim3(256), 0,
                     stream, xz, xy, yz, planesT);
  hipLaunchKernelGGL(precompute_wc, dim3(IN_DIM + 1), dim3(IN_DIM), 0, stream,
                     W_v, b_v, W_out, WcT, bc);
  hipLaunchKernelGGL(fused_sample, dim3(NPTS / 8), dim3(256), 0, stream, qpos,
                     planesT, W_off, b_off, W_wt, b_wt, waux, swtg, out);
  hipLaunchKernelGGL(out_gemm, dim3(NPTS / 32), dim3(256), 0, stream, waux,
                     swtg, WcT, bc, b_out, out);
}